// Round 3
// baseline (78.682 us; speedup 1.0000x reference)
//
#include <hip/hip_runtime.h>

// Chamfer distance, B=4, N=M=8192, D=3, fp32.
// R14: anti-spill mega. R11/R12/R13 all held ~8 concurrent "=&v" asm blocks
// (unroll 4 x WNT) -> up to 256 VGPRs of transient demand; under the
// launch_bounds 128-reg cap that likely spilled to scratch (invisible in
// top-5 counters, explains the structure-invariant ~30us mega). Now:
// #pragma unroll 1 + manual one-iteration LDS prefetch (n0/n1 loaded while
// a0/a1's min3 stream issues, branchless clamped index). Steady-state live
// set ~120 VGPR -> no spill at 4 waves/SIMD. Payload math, fold order,
// part layout, reduce identical to R13 (absmax 0.0).
//   -2h.h | -2l.h | -2h.l | qn.1 | 1.tn | 0
//   query vec:  [ax,ay,az, cx,cy,cz, ax,ay,az, qn1,qn2,qn3, 1,1,1, 0]
//   target vec: [hx,hy,hz, hx,hy,hz, lx,ly,lz, 1,1,1, tn1,tn2,tn3, 0]

typedef __attribute__((ext_vector_type(8)))  short short8;
typedef __attribute__((ext_vector_type(16))) float f32x16;

#define BATCH 4
#define NPTS 8192
#define TOTALQ (BATCH * NPTS)   // 32768
#define BLK 256
#define WNT 2                   // 32-col B tiles per wave -> 64 queries/wave
#define BCOLS (4 * WNT * 32)    // 256 query cols per block (4 waves)
#define NCHUNK (TOTALQ / BCOLS) // 128 (32 chunks per batch)
#define MSPLIT 8                // target slices per batch
#define MC (NPTS / MSPLIT)      // 1024 targets per block, single LDS stage
#define MT_PER (MC / 32)        // 32 target tiles

__device__ __forceinline__ unsigned short f2bf(float f) {  // RTN-even
    unsigned int u = __float_as_uint(f);
    u += 0x7FFFu + ((u >> 16) & 1u);
    return (unsigned short)(u >> 16);
}
__device__ __forceinline__ float bf2f(unsigned short h) {
    return __uint_as_float(((unsigned int)h) << 16);
}
__device__ __forceinline__ unsigned int pk2(unsigned short a, unsigned short b) {
    return (unsigned int)a | ((unsigned int)b << 16);
}

struct Payload {
    unsigned short hx, hy, hz, lx, ly, lz, n1, n2, n3;
};
__device__ __forceinline__ Payload split_point(float x, float y, float z) {
    Payload P;
    P.hx = f2bf(x);  P.hy = f2bf(y);  P.hz = f2bf(z);
    P.lx = f2bf(x - bf2f(P.hx));
    P.ly = f2bf(y - bf2f(P.hy));
    P.lz = f2bf(z - bf2f(P.hz));
    float nrm = fmaf(z, z, fmaf(y, y, x * x));
    P.n1 = f2bf(nrm);
    float r1 = nrm - bf2f(P.n1);
    P.n2 = f2bf(r1);
    P.n3 = f2bf(r1 - bf2f(P.n2));
    return P;
}

__global__ __launch_bounds__(BLK, 4) void chamfer_mega_kernel(
        const float* __restrict__ pred, const float* __restrict__ target,
        float* __restrict__ part, float* __restrict__ out)
{
    const int dir = blockIdx.z;
    const float* __restrict__ Q  = dir ? target : pred;   // outputs (B cols)
    const float* __restrict__ Tg = dir ? pred : target;   // min-over (A rows, LDS)

    const int nch = blockIdx.x;            // 0..127 (256-query-col chunk)
    const int b   = nch >> 5;              // batch (32 chunks per batch)
    const int ms  = blockIdx.y;            // 0..7 target slice
    const int w    = threadIdx.x >> 6;
    const int lane = threadIdx.x & 63;
    const int c = lane & 31;               // row (A) / col (B) within tile
    const int g = lane >> 5;               // k-half
    const unsigned short ONE = 0x3F80;

    if (blockIdx.x == 0 && blockIdx.y == 0 && blockIdx.z == 0 &&
        threadIdx.x == 0) out[0] = 0.0f;   // consumed after kernel boundary

    __shared__ uint4 ldsb[2][MC];          // 32 KB (two k-halves)

    // ---- stage MC target points: raw read -> payload -> LDS (A operand) ----
    #pragma unroll
    for (int j = 0; j < MC / BLK; ++j) {
        int p = j * BLK + threadIdx.x;
        size_t gp = (size_t)b * NPTS + (size_t)ms * MC + p;
        float x = Tg[3 * gp], y = Tg[3 * gp + 1], z = Tg[3 * gp + 2];
        Payload P = split_point(x, y, z);
        ldsb[0][p] = (uint4){ pk2(P.hx, P.hy), pk2(P.hz, P.hx),
                              pk2(P.hy, P.hz), pk2(P.lx, P.ly) };
        ldsb[1][p] = (uint4){ pk2(P.lz, ONE), pk2(ONE, ONE),
                              pk2(P.n1, P.n2), pk2(P.n3, 0) };
    }

    // ---- B fragments (queries): in-register pack, col = colstart + nt*32 + c ----
    const int colstart = nch * BCOLS + w * (WNT * 32);
    short8 bq[WNT];
    #pragma unroll
    for (int nt = 0; nt < WNT; ++nt) {
        int r = colstart + nt * 32 + c;
        float x = Q[3 * r], y = Q[3 * r + 1], z = Q[3 * r + 2];
        Payload P = split_point(x, y, z);
        unsigned short ax = f2bf(-2.f * bf2f(P.hx)),
                       ay = f2bf(-2.f * bf2f(P.hy)),
                       az = f2bf(-2.f * bf2f(P.hz));
        unsigned short cx = f2bf(-2.f * bf2f(P.lx)),
                       cy = f2bf(-2.f * bf2f(P.ly)),
                       cz = f2bf(-2.f * bf2f(P.lz));
        uint4 h0 = { pk2(ax, ay), pk2(az, cx), pk2(cy, cz), pk2(ax, ay) };
        uint4 h1 = { pk2(az, P.n1), pk2(P.n2, P.n3), pk2(ONE, ONE), pk2(ONE, 0) };
        uint4 sel = g ? h1 : h0;
        bq[nt] = *(short8*)&sel;
    }

    f32x16 acc[WNT];
    #pragma unroll
    for (int nt = 0; nt < WNT; ++nt)
        #pragma unroll
        for (int r = 0; r < 16; ++r) acc[nt][r] = 3.4e38f;

    f32x16 vzero;
    #pragma unroll
    for (int r = 0; r < 16; ++r) vzero[r] = 0.0f;

    __syncthreads();

    const ushort* ldsu = (const ushort*)&ldsb[g][0];   // this lane's k-half

    // ---- main loop: manual 1-iter LDS prefetch; 2 ds_read + 4 MFMA + 32 min3
    short8 a0 = *(const short8*)(ldsu + (0 * 32 + c) * 8);
    short8 a1 = *(const short8*)(ldsu + (1 * 32 + c) * 8);
    #pragma unroll 1
    for (int mt = 0; mt < MT_PER; mt += 2) {
        // prefetch next tile pair (clamped, branchless; last-iter loads are
        // valid-but-unused re-reads of tile 0/1)
        const int nmt = (mt + 2 < MT_PER) ? mt + 2 : 0;
        short8 n0 = *(const short8*)(ldsu + (nmt * 32 + c) * 8);
        short8 n1 = *(const short8*)(ldsu + ((nmt + 1) * 32 + c) * 8);
        #pragma unroll
        for (int nt = 0; nt < WNT; ++nt) {
            f32x16 d0, d1;
            // A = target tile (LDS), B = query tile (regs); VGPR dst.
            // s_nop pads the MFMA-write -> VALU-read hazard (asm is opaque
            // to the hazard recognizer).
            asm("v_mfma_f32_32x32x16_bf16 %0, %2, %4, %5\n\t"
                "v_mfma_f32_32x32x16_bf16 %1, %3, %4, %5\n\t"
                "s_nop 7\n\t"
                "s_nop 7"
                : "=&v"(d0), "=&v"(d1)
                : "v"(a0), "v"(a1), "v"(bq[nt]), "v"(vzero));
            #pragma unroll
            for (int r = 0; r < 16; ++r)
                acc[nt][r] = fminf(fminf(acc[nt][r], d0[r]), d1[r]); // v_min3
        }
        a0 = n0;
        a1 = n1;
    }

    // ---- epilogue: min over the 16 regs (rows) in-lane + 1 shfl for g ----
    float* rp = part + (size_t)(dir * MSPLIT + ms) * TOTALQ;
    #pragma unroll
    for (int nt = 0; nt < WNT; ++nt) {
        f32x16 v = acc[nt];
        float m0 = fminf(fminf(v[0],  v[1]),  fminf(v[2],  v[3]));
        float m1 = fminf(fminf(v[4],  v[5]),  fminf(v[6],  v[7]));
        float m2 = fminf(fminf(v[8],  v[9]),  fminf(v[10], v[11]));
        float m3 = fminf(fminf(v[12], v[13]), fminf(v[14], v[15]));
        float m  = fminf(fminf(m0, m1), fminf(m2, m3));
        m = fminf(m, __shfl_xor(m, 32, 64));    // fold the two k-half rows
        if (g == 0) rp[colstart + nt * 32 + c] = m;
    }
}

__global__ __launch_bounds__(BLK) void chamfer_reduce_kernel(
        const float* __restrict__ part, float* __restrict__ out)
{
    int gl = blockIdx.x * BLK + threadIdx.x;   // 0..65535
    int dir = gl >> 15, i = gl & (TOTALQ - 1);

    const float* p = part + (size_t)dir * MSPLIT * TOTALQ + i;
    float m = p[0];
    #pragma unroll
    for (int s = 1; s < MSPLIT; ++s)
        m = fminf(m, p[(size_t)s * TOTALQ]);

    float acc = m * (1.0f / (float)TOTALQ);
    #pragma unroll
    for (int off = 32; off > 0; off >>= 1)
        acc += __shfl_down(acc, off, 64);
    __shared__ float wsum[BLK / 64];
    int lane = threadIdx.x & 63, wid = threadIdx.x >> 6;
    if (lane == 0) wsum[wid] = acc;
    __syncthreads();
    if (threadIdx.x == 0) {
        float s = 0.0f;
        #pragma unroll
        for (int wv = 0; wv < BLK / 64; ++wv) s += wsum[wv];
        atomicAdd(out, s);
    }
}

extern "C" void kernel_launch(void* const* d_in, const int* in_sizes, int n_in,
                              void* d_out, int out_size, void* d_ws, size_t ws_size,
                              hipStream_t stream) {
    const float* pred   = (const float*)d_in[0];
    const float* target = (const float*)d_in[1];
    float*       out    = (float*)d_out;
    float*       part   = (float*)d_ws;   // 2 dirs x 8 slices x 32768 = 2 MB

    dim3 grid(NCHUNK, MSPLIT, 2);   // 128 x 8 x 2 = 2048 blocks
    hipLaunchKernelGGL(chamfer_mega_kernel, grid, dim3(BLK), 0, stream,
                       pred, target, part, out);

    hipLaunchKernelGGL(chamfer_reduce_kernel, dim3(2 * TOTALQ / BLK), dim3(BLK),
                       0, stream, (const float*)part, out);
}